// Round 9
// baseline (1499.922 us; speedup 1.0000x reference)
//
#include <hip/hip_runtime.h>

// Problem constants
#define B_    64
#define T_    512
#define KDIM  1024
#define HID_  1024

// R21 GEMM geometry: identical to R20 (64x64 tile, 256 threads, 4x4/thread,
// BK=16, LDA=20 both regions). Changes are scheduling-only: slice loop
// unrolled x2 with explicit buffer names, tail peeled, pointer-bumped
// global staging.
#define BM 64     // t rows per block
#define BN 64     // h cols per block
#define BK 16     // one numpy 16-k block per slice
#define LDA 20    // padded LDS row: 16+4 floats (5 quads, odd -> reads clean)
#define NSL 64    // slices per block = KDIM/BK
#define BNOFF 1280  // B region offset within a buffer (64*20 floats)
#define BUFSZ 2560  // per-buffer floats: A 64x20 + B 64x20
// total smem = 2*2560 = 5120 floats = 20480 B -> 7 blocks/CU by LDS

// f32 correctly rounded from python float math.exp(-1.0/20.0)
#define ALPHA_F 0.95122942450071400909f

typedef float v4f __attribute__((ext_vector_type(4)));
typedef float v2f __attribute__((ext_vector_type(2)));

// Bit-faithful replication of the harness numpy f32 reference: per output
// element 4 f32 accumulator lanes (lane l sums k = l mod 4), 16-k blocks
// ascending (slices ascending), q descending within block, mul/add separately
// rounded (no FMA), hadd tree (l0+l1)+(l2+l3), one f32 bias add (in the scan
// kernel, same rounding position), f32 scan. Chain identical to R6..R20
// (R16..R20 all PASSED with this split).
//
// R21 vs R20 (GEMM 1345 us, VALUBusy 84%): R20 is issue-saturated — per
// slice/thread 256 mandatory pk-MACs + ~32 ds_read + ~14 addr/select VALU;
// VALUBusy 84% ~= the MAC instruction fraction. Floor = 874 us pure MAC.
// R21 removes the identified non-MAC VALU: (1) slice loop unrolled x2 with
// explicit AB0/AB1 (no (s&1) cndmask selects; all LDS addrs compile-time
// base+imm); (2) last two slices peeled (main loop condition-free);
// (3) global staging pointers bumped += BK (no nk recompute). Datapath,
// LDS layout, rounding chain untouched. Scan: prefetch 16 -> 32 deep
// (4 waves/CU is algorithm-fixed; only in-flight depth can hide latency).
__global__ __launch_bounds__(256, 2) void snn_gemm_np(
    const float* __restrict__ x,     // [B,T,K] f32
    const float* __restrict__ W,     // [H,K] f32
    float* __restrict__ Iout)        // [B,T,H] f32 out (I, no bias)
{
#pragma clang fp contract(off)       // numpy SSE path has no FMA: mul+add only
    __shared__ float smem[2 * BUFSZ];   // 20480 B
    float* const AB0 = smem;            // A @0, B @1280
    float* const AB1 = smem + BUFSZ;

    const int tid = threadIdx.x;
    const int bb  = blockIdx.x;         // batch index
    const int t0  = blockIdx.y * BM;    // t tile origin
    const int h0  = blockIdx.z * BN;    // h tile origin

    const int tx = tid & 15;            // h micro (4 cols, stride 16)
    const int ty = tid >> 4;            // t micro (4 rows, stride 16)

    const int sr = tid >> 2;            // staging row 0..63
    const int sc = (tid & 3) << 2;      // staging col 0,4,8,12

    // per-thread global staging pointers, bumped by BK per slice
    const float* xs = x + ((size_t)bb * T_ + t0 + sr) * KDIM + sc;
    const float* Ws = W + ((size_t)(h0 + sr)) * KDIM + sc;

    // numpy 4-lane accumulators, lane-paired: p01 = lanes {0,1}, p23 = {2,3}
    v2f p01[4][4], p23[4][4];
#pragma unroll
    for (int j = 0; j < 4; ++j)
#pragma unroll
        for (int i = 0; i < 4; ++i) {
            p01[j][i] = (v2f)(0.0f);
            p23[j][i] = (v2f)(0.0f);
        }

// compute one BK=16 slice from buffer BUF: q=3..0 descending, per-lane
// acc += a[4q+l]*b[4q+l], packed mul then packed add — bitwise equal to
// numpy's chained a0b0+(a1b1+(a2b2+(a3b3+acc)))
#define COMPUTE_SLICE(BUF)                                                  \
    {                                                                       \
        _Pragma("unroll")                                                   \
        for (int q = 3; q >= 0; --q) {                                      \
            const int qc = q << 2;                                          \
            v2f a01[4], a23[4], b01[4], b23[4];                             \
            _Pragma("unroll")                                               \
            for (int j = 0; j < 4; ++j) {                                   \
                const v4f a = *(const v4f*)&BUF[(ty + 16 * j) * LDA + qc];  \
                a01[j] = a.xy; a23[j] = a.zw;                               \
            }                                                               \
            _Pragma("unroll")                                               \
            for (int i = 0; i < 4; ++i) {                                   \
                const v4f b =                                               \
                    *(const v4f*)&BUF[BNOFF + (tx + 16 * i) * LDA + qc];    \
                b01[i] = b.xy; b23[i] = b.zw;                               \
            }                                                               \
            _Pragma("unroll")                                               \
            for (int j = 0; j < 4; ++j)                                     \
                _Pragma("unroll")                                           \
                for (int i = 0; i < 4; ++i) {                               \
                    const v2f m01 = a01[j] * b01[i];  /* packed rnd muls */ \
                    const v2f m23 = a23[j] * b23[i];                        \
                    p01[j][i] = p01[j][i] + m01;      /* packed rnd adds */ \
                    p23[j][i] = p23[j][i] + m23;                            \
                }                                                           \
        }                                                                   \
    }

    // ---- prologue: slice 0 -> AB0; slice 1 -> regs; xs/Ws -> slice 2 ----
    float4 pa, pw;
    pa = *(const float4*)xs;
    pw = *(const float4*)Ws;
    *(float4*)&AB0[sr * LDA + sc]         = pa;
    *(float4*)&AB0[BNOFF + sr * LDA + sc] = pw;
    pa = *(const float4*)(xs + BK);
    pw = *(const float4*)(Ws + BK);
    xs += 2 * BK;
    Ws += 2 * BK;
    __syncthreads();                    // AB0 visible

    // main loop: slice pairs (2k, 2k+1), k = 0..30 — fully condition-free.
    // even slice: commit regs (slice 2k+1) -> AB1, load slice 2k+2, compute AB0
    // odd  slice: commit regs (slice 2k+2) -> AB0, load slice 2k+3, compute AB1
    for (int k = 0; k < 31; ++k) {
        *(float4*)&AB1[sr * LDA + sc]         = pa;
        *(float4*)&AB1[BNOFF + sr * LDA + sc] = pw;
        pa = *(const float4*)xs;
        pw = *(const float4*)Ws;
        xs += BK; Ws += BK;
        COMPUTE_SLICE(AB0);
        __syncthreads();   // even-slice reads done; odd-slice commit visible

        *(float4*)&AB0[sr * LDA + sc]         = pa;
        *(float4*)&AB0[BNOFF + sr * LDA + sc] = pw;
        pa = *(const float4*)xs;
        pw = *(const float4*)Ws;
        xs += BK; Ws += BK;
        COMPUTE_SLICE(AB1);
        __syncthreads();   // odd-slice reads done; even-slice commit visible
    }
    // peeled tail: slice 62 (commit slice 63 -> AB1, no more loads), slice 63
    *(float4*)&AB1[sr * LDA + sc]         = pa;
    *(float4*)&AB1[BNOFF + sr * LDA + sc] = pw;
    COMPUTE_SLICE(AB0);
    __syncthreads();
    COMPUTE_SLICE(AB1);
#undef COMPUTE_SLICE

    // epilogue: hadd (l0+l1)+(l2+l3); store I (bias added in scan kernel)
    float* const Ob = Iout + ((size_t)bb * T_ + t0) * HID_ + h0;
#pragma unroll
    for (int j = 0; j < 4; ++j)
#pragma unroll
        for (int i = 0; i < 4; ++i) {
            const float s01 = p01[j][i].x + p01[j][i].y;
            const float s23 = p23[j][i].x + p23[j][i].y;
            Ob[(ty + 16 * j) * HID_ + tx + 16 * i] = s01 + s23;
        }
}

// LIF scan, in place over the spikes buffer (each thread owns one (b,h)
// column: strictly read-then-overwrite within the thread, no cross-thread
// sharing). Bias added here: It = s + b (same rounding position as the fused
// version's (s01+s23)+b), then mem = alpha*mem + It — chain unchanged.
// 32-deep register prefetch (4 waves/CU is fixed by the 65536 scan columns;
// only in-flight load depth can hide HBM/L3 latency); arrays fully unrolled
// -> static indices, no scratch.
__global__ __launch_bounds__(256, 2) void snn_scan(
    float* __restrict__ IS,          // in: I (no bias) / out: spikes, in place
    const float* __restrict__ bias,  // [H]
    float* __restrict__ memf)        // [B,H] f32 out
{
#pragma clang fp contract(off)       // alpha*mem + It must be mul then add
    const int gid = blockIdx.x * 256 + threadIdx.x;
    const int b = gid >> 10;
    const int h = gid & (HID_ - 1);
    float* col = IS + (size_t)b * T_ * HID_ + h;
    const float bv = bias[h];
    float mem = 0.0f;

    float cur[32], nxt[32];
#pragma unroll
    for (int k = 0; k < 32; ++k) cur[k] = col[(size_t)k * HID_];

    for (int tg = 0; tg < T_; tg += 32) {
        if (tg + 32 < T_) {
#pragma unroll
            for (int k = 0; k < 32; ++k)
                nxt[k] = col[(size_t)(tg + 32 + k) * HID_];
        }
#pragma unroll
        for (int k = 0; k < 32; ++k) {
            const float It = cur[k] + bv;     // rounded bias add
            const float am = ALPHA_F * mem;   // rounded mul
            mem = am + It;                    // rounded add
            const bool fire = (mem >= 1.0f);
            col[(size_t)(tg + k) * HID_] = fire ? 1.0f : 0.0f;
            if (fire) mem = 0.0f;
        }
#pragma unroll
        for (int k = 0; k < 32; ++k) cur[k] = nxt[k];
    }
    memf[(size_t)b * HID_ + h] = mem;
}

extern "C" void kernel_launch(void* const* d_in, const int* in_sizes, int n_in,
                              void* d_out, int out_size, void* d_ws, size_t ws_size,
                              hipStream_t stream) {
    const float* x    = (const float*)d_in[0];   // [B,T,K] f32
    const float* W    = (const float*)d_in[1];   // [H,K] f32
    const float* bias = (const float*)d_in[2];   // [H] f32
    float* out    = (float*)d_out;
    float* spikes = out;                          // [B,T,H]
    float* memf   = out + (size_t)B_ * T_ * HID_; // [B,H]

    dim3 g1(B_, T_ / BM, HID_ / BN);   // 64 x 8 x 16 = 8192 blocks
    snn_gemm_np<<<g1, dim3(256), 0, stream>>>(x, W, spikes);

    snn_scan<<<dim3((B_ * HID_) / 256), dim3(256), 0, stream>>>(
        spikes, bias, memf);
}

// Round 10
// 1463.158 us; speedup vs baseline: 1.0251x; 1.0251x over previous
//
#include <hip/hip_runtime.h>

// Problem constants
#define B_    64
#define T_    512
#define KDIM  1024
#define HID_  1024

// R22 = R20 GEMM (verbatim) + R21 scan (verbatim).
// R20 GEMM geometry: 64x64 tile, 256 threads (4 waves), 4x4/thread, BK=16.
#define BM 64     // t rows per block
#define BN 64     // h cols per block
#define BK 16     // one numpy 16-k block per slice
#define LDA 20    // padded LDS row: 16+4 floats (5 quads, odd -> reads clean)
#define NSL 64    // slices per block = KDIM/BK
#define BNOFF 1280  // B region offset within a buffer (64*20 floats)
#define BUFSZ 2560  // per-buffer floats: A 64x20 + B 64x20
// total smem = 2*2560 = 5120 floats = 20480 B -> 7 blocks/CU by LDS

// f32 correctly rounded from python float math.exp(-1.0/20.0)
#define ALPHA_F 0.95122942450071400909f

typedef float v4f __attribute__((ext_vector_type(4)));
typedef float v2f __attribute__((ext_vector_type(2)));

// Bit-faithful replication of the harness numpy f32 reference: per output
// element 4 f32 accumulator lanes (lane l sums k = l mod 4), 16-k blocks
// ascending (slices ascending), q descending within block, mul/add separately
// rounded (no FMA), hadd tree (l0+l1)+(l2+l3), one f32 bias add (in the scan
// kernel, same rounding position), f32 scan. Chain identical to R6..R21
// (R16..R21 all PASSED with this split).
//
// R22 rationale: R21's unroll cut busy 1130->1058 us but grew VGPR 72->88,
// dropping the per-SIMD wave ceiling 7->5 (floor(512/VGPR), ~8-granular):
// occupancy 34->23%, idle +163 us, net regression. The register budget at
// this design point is exactly 72 = 64 acc + 8 staging — any extra live reg
// costs a wave slot, and wave slots beat issue slots. So GEMM reverts to the
// R20 body verbatim (72 VGPR, 1345 us, VALUBusy 84%, ~15-20% above the
// no-FMA issue roofline at sustained clock). The scan keeps R21's 32-deep
// prefetch (total-GEMM = 64 us, near the 268 MB / 6.3 TB/s = 43 us floor).
__global__ __launch_bounds__(256, 2) void snn_gemm_np(
    const float* __restrict__ x,     // [B,T,K] f32
    const float* __restrict__ W,     // [H,K] f32
    float* __restrict__ Iout)        // [B,T,H] f32 out (I, no bias)
{
#pragma clang fp contract(off)       // numpy SSE path has no FMA: mul+add only
    __shared__ float smem[2 * BUFSZ];   // 20480 B
    float* const AB0 = smem;            // A @0, B @1280
    float* const AB1 = smem + BUFSZ;

    const int tid = threadIdx.x;
    const int bb  = blockIdx.x;         // batch index
    const int t0  = blockIdx.y * BM;    // t tile origin
    const int h0  = blockIdx.z * BN;    // h tile origin

    const int tx = tid & 15;            // h micro (4 cols, stride 16)
    const int ty = tid >> 4;            // t micro (4 rows, stride 16)

    const int sr = tid >> 2;            // staging row 0..63
    const int sc = (tid & 3) << 2;      // staging col 0,4,8,12

    const float* xb = x + ((size_t)bb * T_ + t0) * KDIM;
    const float* Wb = W + (size_t)h0 * KDIM;

    // ---- prologue: slice 0 -> AB0; slice 1 -> regs ----
    float4 pa, pw;
    pa = *(const float4*)&xb[(size_t)sr * KDIM + sc];
    pw = *(const float4*)&Wb[(size_t)sr * KDIM + sc];
    *(float4*)&AB0[sr * LDA + sc]         = pa;
    *(float4*)&AB0[BNOFF + sr * LDA + sc] = pw;
    pa = *(const float4*)&xb[(size_t)sr * KDIM + 16 + sc];
    pw = *(const float4*)&Wb[(size_t)sr * KDIM + 16 + sc];
    __syncthreads();                    // AB0 visible

    // numpy 4-lane accumulators, lane-paired: p01 = lanes {0,1}, p23 = {2,3}
    v2f p01[4][4], p23[4][4];
#pragma unroll
    for (int j = 0; j < 4; ++j)
#pragma unroll
        for (int i = 0; i < 4; ++i) {
            p01[j][i] = (v2f)(0.0f);
            p23[j][i] = (v2f)(0.0f);
        }

    for (int s = 0; s < NSL; ++s) {
        float* const cb = (s & 1) ? AB1 : AB0;   // compute buffer (slice s)
        float* const nb = (s & 1) ? AB0 : AB1;   // commit target (slice s+1)

        // 1) commit regs (slice s+1) into nb — overlapped with compute;
        //    nb's old readers finished before the previous barrier.
        if (s + 1 < NSL) {
            *(float4*)&nb[sr * LDA + sc]         = pa;
            *(float4*)&nb[BNOFF + sr * LDA + sc] = pw;
        }
        // 2) issue slice s+2 loads; a whole compute phase to land.
        if (s + 2 < NSL) {
            const int nk = (s + 2) << 4;
            pa = *(const float4*)&xb[(size_t)sr * KDIM + nk + sc];
            pw = *(const float4*)&Wb[(size_t)sr * KDIM + nk + sc];
        }
        // 3) compute slice s: one numpy 16-k block; q=3..0 —
        // per-lane acc += a[4q+l]*b[4q+l], mul then add: bitwise equal to
        // numpy's chained a0b0+(a1b1+(a2b2+(a3b3+acc)))
#pragma unroll
        for (int q = 3; q >= 0; --q) {
            const int qc = q << 2;
            v2f a01[4], a23[4], b01[4], b23[4];
#pragma unroll
            for (int j = 0; j < 4; ++j) {
                const v4f a = *(const v4f*)&cb[(ty + 16 * j) * LDA + qc];
                a01[j] = a.xy; a23[j] = a.zw;
            }
#pragma unroll
            for (int i = 0; i < 4; ++i) {
                const v4f b = *(const v4f*)&cb[BNOFF + (tx + 16 * i) * LDA + qc];
                b01[i] = b.xy; b23[i] = b.zw;
            }
#pragma unroll
            for (int j = 0; j < 4; ++j)
#pragma unroll
                for (int i = 0; i < 4; ++i) {
                    const v2f m01 = a01[j] * b01[i];   // packed rounded muls
                    const v2f m23 = a23[j] * b23[i];
                    p01[j][i] = p01[j][i] + m01;       // packed rounded adds
                    p23[j][i] = p23[j][i] + m23;
                }
        }
        __syncthreads();   // slice s reads done; slice s+1 commit visible
    }

    // epilogue: hadd (l0+l1)+(l2+l3); store I (bias added in scan kernel)
    float* const Ob = Iout + ((size_t)bb * T_ + t0) * HID_ + h0;
#pragma unroll
    for (int j = 0; j < 4; ++j)
#pragma unroll
        for (int i = 0; i < 4; ++i) {
            const float s01 = p01[j][i].x + p01[j][i].y;
            const float s23 = p23[j][i].x + p23[j][i].y;
            Ob[(ty + 16 * j) * HID_ + tx + 16 * i] = s01 + s23;
        }
}

// LIF scan, in place over the spikes buffer (each thread owns one (b,h)
// column: strictly read-then-overwrite within the thread, no cross-thread
// sharing). Bias added here: It = s + b (same rounding position as the fused
// version's (s01+s23)+b), then mem = alpha*mem + It — chain unchanged.
// 32-deep register prefetch (4 waves/CU is fixed by the 65536 scan columns;
// only in-flight load depth can hide HBM/L3 latency); arrays fully unrolled
// -> static indices, no scratch. Measured ~64 us in R21 (roofline ~43 us).
__global__ __launch_bounds__(256, 2) void snn_scan(
    float* __restrict__ IS,          // in: I (no bias) / out: spikes, in place
    const float* __restrict__ bias,  // [H]
    float* __restrict__ memf)        // [B,H] f32 out
{
#pragma clang fp contract(off)       // alpha*mem + It must be mul then add
    const int gid = blockIdx.x * 256 + threadIdx.x;
    const int b = gid >> 10;
    const int h = gid & (HID_ - 1);
    float* col = IS + (size_t)b * T_ * HID_ + h;
    const float bv = bias[h];
    float mem = 0.0f;

    float cur[32], nxt[32];
#pragma unroll
    for (int k = 0; k < 32; ++k) cur[k] = col[(size_t)k * HID_];

    for (int tg = 0; tg < T_; tg += 32) {
        if (tg + 32 < T_) {
#pragma unroll
            for (int k = 0; k < 32; ++k)
                nxt[k] = col[(size_t)(tg + 32 + k) * HID_];
        }
#pragma unroll
        for (int k = 0; k < 32; ++k) {
            const float It = cur[k] + bv;     // rounded bias add
            const float am = ALPHA_F * mem;   // rounded mul
            mem = am + It;                    // rounded add
            const bool fire = (mem >= 1.0f);
            col[(size_t)(tg + k) * HID_] = fire ? 1.0f : 0.0f;
            if (fire) mem = 0.0f;
        }
#pragma unroll
        for (int k = 0; k < 32; ++k) cur[k] = nxt[k];
    }
    memf[(size_t)b * HID_ + h] = mem;
}

extern "C" void kernel_launch(void* const* d_in, const int* in_sizes, int n_in,
                              void* d_out, int out_size, void* d_ws, size_t ws_size,
                              hipStream_t stream) {
    const float* x    = (const float*)d_in[0];   // [B,T,K] f32
    const float* W    = (const float*)d_in[1];   // [H,K] f32
    const float* bias = (const float*)d_in[2];   // [H] f32
    float* out    = (float*)d_out;
    float* spikes = out;                          // [B,T,H]
    float* memf   = out + (size_t)B_ * T_ * HID_; // [B,H]

    dim3 g1(B_, T_ / BM, HID_ / BN);   // 64 x 8 x 16 = 8192 blocks
    snn_gemm_np<<<g1, dim3(256), 0, stream>>>(x, W, spikes);

    snn_scan<<<dim3((B_ * HID_) / 256), dim3(256), 0, stream>>>(
        spikes, bias, memf);
}